// Round 1
// baseline (119.706 us; speedup 1.0000x reference)
//
#include <hip/hip_runtime.h>

#define NSTEP  730
#define NGRID  2000
#define MU_    16
#define CH     10          // chunk length; 730 = 73 * 10
#define NCHUNK (NSTEP / CH)
#define PRECSf 1e-5f

__device__ __forceinline__ float fast_exp2(float v) {
#if __has_builtin(__builtin_amdgcn_exp2f)
    return __builtin_amdgcn_exp2f(v);   // v_exp_f32
#else
    return exp2f(v);
#endif
}
__device__ __forceinline__ float fast_log2(float v) {
#if __has_builtin(__builtin_amdgcn_logf)
    return __builtin_amdgcn_logf(v);    // v_log_f32 (log2)
#else
    return log2f(v);
#endif
}

__global__ __launch_bounds__(64, 1)
void hbv_kernel(const float* __restrict__ x,
                const float* __restrict__ params,
                float* __restrict__ out)
{
    const int tid = blockIdx.x * 64 + threadIdx.x;
    const int g = tid >> 4;   // grid cell
    const int m = tid & 15;   // ensemble member
    if (g >= NGRID) return;

    // --- parameter de-normalization (one-time) ---
    const float lo[13] = {1.f,50.f,0.05f,0.01f,0.001f,0.2f,0.f,0.f,-2.5f,0.5f,0.f,0.f,0.3f};
    const float hi[13] = {6.f,1000.f,0.9f,0.5f,0.2f,1.f,10.f,100.f,2.5f,10.f,0.1f,0.2f,5.f};
    float p[13];
    const float* pg = params + ((size_t)g * 13) * MU_ + m;
#pragma unroll
    for (int i = 0; i < 13; ++i) p[i] = lo[i] + pg[(size_t)i * MU_] * (hi[i] - lo[i]);

    const float parBETA = p[0],  parFC    = p[1],  parK0  = p[2],  parK1 = p[3];
    const float parK2   = p[4],  parLP    = p[5],  parPERC= p[6],  parUZL= p[7];
    const float parTT   = p[8],  parCFMAX = p[9],  parCFR = p[10];
    const float parCWH  = p[11], parBETAET= p[12];

    const float invFC   = 1.0f / parFC;
    const float invLPFC = 1.0f / (parLP * parFC);
    const float cfrXcf  = parCFR * parCFMAX;

    float SP = 0.001f, MW = 0.001f, SM = 0.001f, SUZ = 0.001f, SLZ = 0.001f;

    const float* xg = x + (size_t)g * 3;

    // double-buffered register prefetch of (P,T,E) per chunk
    float bufA[CH][3], bufB[CH][3];
#pragma unroll
    for (int i = 0; i < CH; ++i) {
        const float* s = xg + (size_t)i * (NGRID * 3);
        bufA[i][0] = s[0]; bufA[i][1] = s[1]; bufA[i][2] = s[2];
    }

#define CHUNK_BODY(CUR, NXT, T0)                                               \
    {                                                                          \
        _Pragma("unroll")                                                      \
        for (int i = 0; i < CH; ++i) {                                         \
            int tn = (T0) + CH + i;                                            \
            tn = tn < NSTEP ? tn : NSTEP - 1;                                  \
            const float* s = xg + (size_t)tn * (NGRID * 3);                    \
            NXT[i][0] = s[0]; NXT[i][1] = s[1]; NXT[i][2] = s[2];              \
        }                                                                      \
        float q[CH];                                                           \
        _Pragma("unroll")                                                      \
        for (int i = 0; i < CH; ++i) {                                         \
            const float Pt = CUR[i][0], Tt = CUR[i][1], Et = CUR[i][2];        \
            const float rain = (Tt >= parTT) ? Pt : 0.0f;                      \
            const float snow = Pt - rain;                                      \
            SP += snow;                                                        \
            const float melt = fminf(fmaxf(parCFMAX * (Tt - parTT), 0.0f), SP);\
            MW += melt; SP -= melt;                                            \
            const float refr = fminf(fmaxf(cfrXcf * (parTT - Tt), 0.0f), MW);  \
            SP += refr; MW -= refr;                                            \
            const float tosoil = fmaxf(MW - parCWH * SP, 0.0f);                \
            MW -= tosoil;                                                      \
            const float sw = fminf(fast_exp2(parBETA * fast_log2(SM * invFC)), 1.0f); \
            const float rech = (rain + tosoil) * sw;                           \
            SM += rain + tosoil - rech;                                        \
            const float excess = fmaxf(SM - parFC, 0.0f);                      \
            SM -= excess;                                                      \
            const float ef = fminf(fast_exp2(parBETAET * fast_log2(SM * invLPFC)), 1.0f); \
            const float ETa = fminf(SM, Et * ef);                              \
            SM = fmaxf(SM - ETa, PRECSf);                                      \
            SUZ += rech + excess;                                              \
            const float PERC = fminf(SUZ, parPERC);                            \
            SUZ -= PERC;                                                       \
            const float Q0 = parK0 * fmaxf(SUZ - parUZL, 0.0f);                \
            SUZ -= Q0;                                                         \
            const float Q1 = parK1 * SUZ;                                      \
            SUZ -= Q1;                                                         \
            SLZ += PERC;                                                       \
            const float Q2 = parK2 * SLZ;                                      \
            SLZ -= Q2;                                                         \
            q[i] = Q0 + Q1 + Q2;                                               \
        }                                                                      \
        _Pragma("unroll")                                                      \
        for (int i = 0; i < CH; ++i) q[i] += __shfl_xor(q[i], 1);              \
        _Pragma("unroll")                                                      \
        for (int i = 0; i < CH; ++i) q[i] += __shfl_xor(q[i], 2);              \
        _Pragma("unroll")                                                      \
        for (int i = 0; i < CH; ++i) q[i] += __shfl_xor(q[i], 4);              \
        _Pragma("unroll")                                                      \
        for (int i = 0; i < CH; ++i) q[i] += __shfl_xor(q[i], 8);              \
        if (m == 0) {                                                          \
            _Pragma("unroll")                                                  \
            for (int i = 0; i < CH; ++i)                                       \
                out[(size_t)((T0) + i) * NGRID + g] = q[i] * 0.0625f;          \
        }                                                                      \
    }

    // 72 chunks in parity pairs (compile-time buffer swap), then chunk 72.
    for (int c = 0; c < NCHUNK - 1; c += 2) {
        const int t0 = c * CH;
        CHUNK_BODY(bufA, bufB, t0);
        CHUNK_BODY(bufB, bufA, t0 + CH);
    }
    CHUNK_BODY(bufA, bufB, (NCHUNK - 1) * CH);
#undef CHUNK_BODY
}

extern "C" void kernel_launch(void* const* d_in, const int* in_sizes, int n_in,
                              void* d_out, int out_size, void* d_ws, size_t ws_size,
                              hipStream_t stream)
{
    const float* x      = (const float*)d_in[0];
    const float* params = (const float*)d_in[1];
    float* out          = (float*)d_out;

    const int total  = NGRID * MU_;          // 32000 threads
    const int block  = 64;
    const int nblock = (total + block - 1) / block;   // 500

    hipLaunchKernelGGL(hbv_kernel, dim3(nblock), dim3(block), 0, stream,
                       x, params, out);
}